// Round 1
// baseline (712.819 us; speedup 1.0000x reference)
//
#include <hip/hip_runtime.h>
#include <hip/hip_bf16.h>

// Shapes (fixed by reference): B=32, T=2048, H=1024, U=1024.
// out = [context (32*1024)][attention_weights (32*2048)]  (fp32)
// V_b is a uniform score shift -> cancels in softmax -> unused.
//
// ws layout (bytes):
//   [0, 128K)          c[b][u] = q.Wq + W_b          (fp32, 32*1024)
//   [128K, 128K+2M)    Wv as bf16 bits [u][h]        (1024*1024 u16)
//   [+2M, +2M+256K)    score[b][t]                   (fp32, 32*2048)
//   [.., +2M)          ctx partials [b][tc=16][h]    (fp32, 2M)
// total ~4.6 MB

#define B_DIM 32
#define T_DIM 2048
#define H_DIM 1024
#define U_DIM 1024

typedef __bf16 bf16x8 __attribute__((ext_vector_type(8)));
typedef float f32x4 __attribute__((ext_vector_type(4)));

__device__ __forceinline__ unsigned short f2bf(float f) {
    unsigned int u = __float_as_uint(f);
    unsigned int r = (u + 0x7FFFu + ((u >> 16) & 1u)) >> 16;   // RNE
    return (unsigned short)r;
}

// ---------- pass 0a: Wv (first H cols of W_w rows) -> bf16 ----------
__global__ void prep_wv_kernel(const float* __restrict__ W_w,
                               unsigned short* __restrict__ wv) {
    int u = blockIdx.x;            // 1024
    int tid = threadIdx.x;         // 256
    float4 x = reinterpret_cast<const float4*>(W_w + (size_t)u * 2 * H_DIM)[tid];
    uint2 p;
    p.x = (unsigned int)f2bf(x.x) | ((unsigned int)f2bf(x.y) << 16);
    p.y = (unsigned int)f2bf(x.z) | ((unsigned int)f2bf(x.w) << 16);
    reinterpret_cast<uint2*>(wv)[(size_t)u * (H_DIM / 4) + tid] = p;
}

// ---------- pass 0b: c[b][u] = q[b] . Wq[u] + W_b[u]  (fp32 exact) ----------
__global__ void prep_c_kernel(const float* __restrict__ q,     // [B][H]
                              const float* __restrict__ W_w,   // [U][2H]
                              const float* __restrict__ W_b,   // [U]
                              float* __restrict__ cvec) {      // [B][U]
    __shared__ float q_sh[H_DIM];
    int b = blockIdx.y;            // 32
    int u0 = blockIdx.x * 128;     // 8 chunks
    int tid = threadIdx.x;         // 128
    for (int i = tid; i < H_DIM / 4; i += 128)
        reinterpret_cast<float4*>(q_sh)[i] =
            reinterpret_cast<const float4*>(q + (size_t)b * H_DIM)[i];
    __syncthreads();
    int u = u0 + tid;
    const float4* wrow = reinterpret_cast<const float4*>(W_w + (size_t)u * 2 * H_DIM + H_DIM);
    float s = 0.f;
#pragma unroll 4
    for (int i = 0; i < H_DIM / 4; i++) {
        float4 wv4 = wrow[i];
        float4 q4 = reinterpret_cast<float4*>(q_sh)[i];
        s += wv4.x * q4.x + wv4.y * q4.y + wv4.z * q4.z + wv4.w * q4.w;
    }
    cvec[(size_t)b * U_DIM + u] = s + W_b[u];
}

// ---------- pass 1: GEMM(values, Wv^T) + tanh + dot(V_w) -> score ----------
// Block: 512 threads = 8 waves. Tile 64(M) x 1024(N=all U). Wave w: N slice [w*128, w*128+128).
// A (values, fp32) staged to LDS as bf16 (read ONCE from HBM), B (Wv bf16) global->reg.
__global__ __launch_bounds__(512, 2)
void gemm_score_kernel(const float* __restrict__ values,        // [B*T][H]
                       const unsigned short* __restrict__ wv,   // bf16 [U][H]
                       const float* __restrict__ cvec,          // [B][U]
                       const float* __restrict__ Vw,            // [U]
                       float* __restrict__ score) {             // [B][T]
    __shared__ unsigned short a_sh[64 * 40];   // 64 rows x 32 k, stride 40 (pad: 2-way only)
    __shared__ float sc_sh[64 * 8];

    const int tid = threadIdx.x;
    const int lane = tid & 63;
    const int w = tid >> 6;          // wave 0..7
    const int col = lane & 15;
    const int quad = lane >> 4;
    const int m0 = blockIdx.x * 64;  // 1024 blocks
    const int b = m0 >> 11;
    const int t0 = m0 & (T_DIM - 1);

    f32x4 acc[4][8];
    const f32x4 zero4 = {0.f, 0.f, 0.f, 0.f};
#pragma unroll
    for (int mt = 0; mt < 4; mt++)
#pragma unroll
        for (int nt = 0; nt < 8; nt++) acc[mt][nt] = zero4;

    const int srow = tid >> 3;           // 0..63
    const int scol = (tid & 7) * 4;      // 0..28
    const float* arow = values + (size_t)(m0 + srow) * H_DIM + scol;
    const unsigned short* bbase = wv + (size_t)(w * 128 + col) * H_DIM + quad * 8;

    // prefetch k=0
    float4 v = *reinterpret_cast<const float4*>(arow);
    bf16x8 bnext[8];
#pragma unroll
    for (int nt = 0; nt < 8; nt++)
        bnext[nt] = *reinterpret_cast<const bf16x8*>(bbase + (size_t)nt * 16 * H_DIM);

    for (int k0 = 0; k0 < H_DIM; k0 += 32) {
        __syncthreads();   // all waves done reading previous A tile
        uint2 p;
        p.x = (unsigned int)f2bf(v.x) | ((unsigned int)f2bf(v.y) << 16);
        p.y = (unsigned int)f2bf(v.z) | ((unsigned int)f2bf(v.w) << 16);
        *reinterpret_cast<uint2*>(&a_sh[srow * 40 + scol]) = p;
        __syncthreads();

        bf16x8 bcur[8];
#pragma unroll
        for (int nt = 0; nt < 8; nt++) bcur[nt] = bnext[nt];

        // prefetch next K-step (wraps harmlessly on last iter)
        const int k1 = (k0 + 32) & (H_DIM - 1);
        v = *reinterpret_cast<const float4*>(arow + k1);
#pragma unroll
        for (int nt = 0; nt < 8; nt++)
            bnext[nt] = *reinterpret_cast<const bf16x8*>(bbase + (size_t)nt * 16 * H_DIM + k1);

        bf16x8 af[4];
#pragma unroll
        for (int mt = 0; mt < 4; mt++)
            af[mt] = *reinterpret_cast<const bf16x8*>(&a_sh[(mt * 16 + col) * 40 + quad * 8]);

#pragma unroll
        for (int nt = 0; nt < 8; nt++)
#pragma unroll
            for (int mt = 0; mt < 4; mt++)
                acc[mt][nt] = __builtin_amdgcn_mfma_f32_16x16x32_bf16(af[mt], bcur[nt],
                                                                      acc[mt][nt], 0, 0, 0);
    }

    // ---- epilogue: score_m = sum_n tanh(pre + c) * Vw[n] ----
    float cv[8], vwv[8];
#pragma unroll
    for (int nt = 0; nt < 8; nt++) {
        int n = w * 128 + nt * 16 + col;
        cv[nt] = cvec[(size_t)b * U_DIM + n];
        vwv[nt] = Vw[n];
    }
#pragma unroll
    for (int mt = 0; mt < 4; mt++) {
#pragma unroll
        for (int j = 0; j < 4; j++) {
            float s = 0.f;
#pragma unroll
            for (int nt = 0; nt < 8; nt++)
                s += tanhf(acc[mt][nt][j] + cv[nt]) * vwv[nt];
            // reduce across the 16 col-lanes (stays within quad)
            s += __shfl_xor(s, 1, 64);
            s += __shfl_xor(s, 2, 64);
            s += __shfl_xor(s, 4, 64);
            s += __shfl_xor(s, 8, 64);
            if (col == 0) sc_sh[(mt * 16 + quad * 4 + j) * 8 + w] = s;
        }
    }
    __syncthreads();
    if (tid < 64) {
        float s = 0.f;
#pragma unroll
        for (int ww = 0; ww < 8; ww++) s += sc_sh[tid * 8 + ww];
        score[(size_t)b * T_DIM + t0 + tid] = s;
    }
}

// ---------- pass 2: softmax over T per batch ----------
__global__ void softmax_kernel(const float* __restrict__ score,
                               float* __restrict__ aw) {
    int b = blockIdx.x;            // 32
    int tid = threadIdx.x;         // 256
    int lane = tid & 63, w = tid >> 6;
    __shared__ float redm[4];
    __shared__ float reds[4];
    float loc[8];
    float m = -1e30f;
#pragma unroll
    for (int i = 0; i < 8; i++) {
        loc[i] = score[(size_t)b * T_DIM + tid + i * 256];
        m = fmaxf(m, loc[i]);
    }
#pragma unroll
    for (int off = 32; off >= 1; off >>= 1) m = fmaxf(m, __shfl_xor(m, off, 64));
    if (lane == 0) redm[w] = m;
    __syncthreads();
    m = fmaxf(fmaxf(redm[0], redm[1]), fmaxf(redm[2], redm[3]));
    float sum = 0.f;
#pragma unroll
    for (int i = 0; i < 8; i++) {
        loc[i] = __expf(loc[i] - m);
        sum += loc[i];
    }
#pragma unroll
    for (int off = 32; off >= 1; off >>= 1) sum += __shfl_xor(sum, off, 64);
    if (lane == 0) reds[w] = sum;
    __syncthreads();
    sum = reds[0] + reds[1] + reds[2] + reds[3];
    float inv = 1.0f / sum;
#pragma unroll
    for (int i = 0; i < 8; i++)
        aw[(size_t)b * T_DIM + tid + i * 256] = loc[i] * inv;
}

// ---------- pass 3a: partial context over t-chunks ----------
__global__ void ctx_partial_kernel(const float* __restrict__ values,
                                   const float* __restrict__ aw,
                                   float* __restrict__ partial) {
    int tc = blockIdx.x;           // 16 chunks of 128 t
    int b = blockIdx.y;            // 32
    int tid = threadIdx.x;         // 256 -> h = tid*4..+3
    const float4* v4 = reinterpret_cast<const float4*>(
                           values + ((size_t)b * T_DIM + tc * 128) * H_DIM) + tid;
    const float* a = aw + (size_t)b * T_DIM + tc * 128;
    float4 acc = make_float4(0.f, 0.f, 0.f, 0.f);
#pragma unroll 4
    for (int t = 0; t < 128; t++) {
        float wgt = a[t];
        float4 vv = v4[(size_t)t * (H_DIM / 4)];
        acc.x += wgt * vv.x; acc.y += wgt * vv.y;
        acc.z += wgt * vv.z; acc.w += wgt * vv.w;
    }
    reinterpret_cast<float4*>(partial + ((size_t)b * 16 + tc) * H_DIM)[tid] = acc;
}

// ---------- pass 3b: combine partials ----------
__global__ void ctx_combine_kernel(const float* __restrict__ partial,
                                   float* __restrict__ ctx) {
    int idx = blockIdx.x * 256 + threadIdx.x;   // 32768
    int b = idx >> 10, h = idx & (H_DIM - 1);
    float s = 0.f;
#pragma unroll
    for (int tc = 0; tc < 16; tc++)
        s += partial[((size_t)b * 16 + tc) * H_DIM + h];
    ctx[idx] = s;
}

extern "C" void kernel_launch(void* const* d_in, const int* in_sizes, int n_in,
                              void* d_out, int out_size, void* d_ws, size_t ws_size,
                              hipStream_t stream) {
    const float* query  = (const float*)d_in[0];   // [1][B][H]
    const float* values = (const float*)d_in[1];   // [B][T][H]
    const float* W_w    = (const float*)d_in[2];   // [U][2H]
    const float* W_b    = (const float*)d_in[3];   // [U]
    const float* V_w    = (const float*)d_in[4];   // [1][U]
    // d_in[5] = V_b: uniform score shift, cancels in softmax -> unused.

    float* out = (float*)d_out;
    char* ws = (char*)d_ws;
    float* cvec            = (float*)(ws);                               // 128 KB
    unsigned short* wv     = (unsigned short*)(ws + 131072);             // 2 MB
    float* score           = (float*)(ws + 131072 + 2097152);            // 256 KB
    float* partial         = (float*)(ws + 131072 + 2097152 + 262144);   // 2 MB
    float* ctx = out;                    // [B][H]
    float* aw  = out + B_DIM * H_DIM;    // [B][T]

    prep_wv_kernel<<<U_DIM, 256, 0, stream>>>(W_w, wv);
    prep_c_kernel<<<dim3(8, B_DIM), 128, 0, stream>>>(query, W_w, (const float*)d_in[3], cvec);
    gemm_score_kernel<<<(B_DIM * T_DIM) / 64, 512, 0, stream>>>(values, wv, cvec, V_w, score);
    softmax_kernel<<<B_DIM, 256, 0, stream>>>(score, aw);
    ctx_partial_kernel<<<dim3(16, B_DIM), 256, 0, stream>>>(values, aw, partial);
    ctx_combine_kernel<<<128, 256, 0, stream>>>(partial, ctx);
}

// Round 2
// 675.034 us; speedup vs baseline: 1.0560x; 1.0560x over previous
//
#include <hip/hip_runtime.h>
#include <hip/hip_bf16.h>

// Shapes (fixed by reference): B=32, T=2048, H=1024, U=1024.
// out = [context (32*1024)][attention_weights (32*2048)]  (fp32)
// V_b is a uniform score shift -> cancels in softmax -> unused.

#define B_DIM 32
#define T_DIM 2048
#define H_DIM 1024
#define U_DIM 1024

typedef __bf16 bf16x8 __attribute__((ext_vector_type(8)));
typedef float f32x4 __attribute__((ext_vector_type(4)));

__device__ __forceinline__ unsigned int f2bf(float f) {
    unsigned int u = __float_as_uint(f);
    return (u + 0x7FFFu + ((u >> 16) & 1u)) >> 16;   // RNE
}

__device__ __forceinline__ float fast_tanh(float x) {
    x = fminf(9.f, fmaxf(-9.f, x));
    float e = __expf(2.f * x);
    return 1.f - 2.f * __frcp_rn(e + 1.f);
}

// ---------- pass 0a: Wv (first H cols of W_w rows) -> bf16 ----------
__global__ void prep_wv_kernel(const float* __restrict__ W_w,
                               unsigned short* __restrict__ wv) {
    int u = blockIdx.x;            // 1024
    int tid = threadIdx.x;         // 256
    float4 x = reinterpret_cast<const float4*>(W_w + (size_t)u * 2 * H_DIM)[tid];
    uint2 p;
    p.x = f2bf(x.x) | (f2bf(x.y) << 16);
    p.y = f2bf(x.z) | (f2bf(x.w) << 16);
    reinterpret_cast<uint2*>(wv)[(size_t)u * (H_DIM / 4) + tid] = p;
}

// ---------- pass 0b: c[b][u] = q[b] . Wq[u] + W_b[u]  (fp32 exact) ----------
// grid (U/64, B), 256 threads = 4 waves; wave handles 16 u's with coalesced loads.
__global__ void prep_c_kernel(const float* __restrict__ q,     // [B][H]
                              const float* __restrict__ W_w,   // [U][2H]
                              const float* __restrict__ W_b,   // [U]
                              float* __restrict__ cvec) {      // [B][U]
    __shared__ float4 q_sh[H_DIM / 4];
    int b = blockIdx.y;
    int u0 = blockIdx.x * 64;
    int tid = threadIdx.x;
    int lane = tid & 63, w = tid >> 6;
    q_sh[tid] = reinterpret_cast<const float4*>(q + (size_t)b * H_DIM)[tid];
    __syncthreads();
#pragma unroll
    for (int i = 0; i < 16; i++) {
        int u = u0 + w * 16 + i;
        const float4* wr = reinterpret_cast<const float4*>(W_w + (size_t)u * 2 * H_DIM + H_DIM);
        float s = 0.f;
#pragma unroll
        for (int j = 0; j < 4; j++) {
            float4 wv4 = wr[j * 64 + lane];
            float4 q4 = q_sh[j * 64 + lane];
            s += wv4.x * q4.x + wv4.y * q4.y + wv4.z * q4.z + wv4.w * q4.w;
        }
#pragma unroll
        for (int off = 32; off >= 1; off >>= 1) s += __shfl_xor(s, off, 64);
        if (lane == 0) cvec[(size_t)b * U_DIM + u] = s + W_b[u];
    }
}

// ---------- pass 1: GEMM(values, Wv^T) + tanh + dot(V_w) -> score ----------
// 512 threads = 8 waves. Tile 64(M) x 1024(N=all U), K-step 64, LDS A double-buffer,
// ONE barrier per K-step. A prefetched global->reg at iter top (covered by 64 MFMA).
__global__ __launch_bounds__(512, 2)
void gemm_score_kernel(const float* __restrict__ values,        // [B*T][H]
                       const unsigned short* __restrict__ wv,   // bf16 [U][H]
                       const float* __restrict__ cvec,          // [B][U]
                       const float* __restrict__ Vw,            // [U]
                       float* __restrict__ score) {             // [B][T]
    // 64 rows x 64 k bf16, row stride 72 (pad 8 -> worst 2-way bank alias = free)
    __shared__ __align__(16) unsigned short a_sh[2][64 * 72];
    __shared__ float sc_sh[64 * 8];

    const int tid = threadIdx.x;
    const int lane = tid & 63;
    const int w = tid >> 6;          // wave 0..7
    const int col = lane & 15;
    const int quad = lane >> 4;
    const int m0 = blockIdx.x * 64;  // 1024 blocks
    const int b = m0 >> 11;
    const int t0 = m0 & (T_DIM - 1);

    f32x4 acc[4][8];
    const f32x4 zero4 = {0.f, 0.f, 0.f, 0.f};
#pragma unroll
    for (int mt = 0; mt < 4; mt++)
#pragma unroll
        for (int nt = 0; nt < 8; nt++) acc[mt][nt] = zero4;

    // staging: thread -> (row = tid>>3, kgroup = tid&7 covering 8 k each)
    const int srow = tid >> 3;
    const int skg = tid & 7;
    const float* aptr = values + (size_t)(m0 + srow) * H_DIM + skg * 8;
    const int sidx = srow * 72 + skg * 8;

    // prologue: stage tile 0 into buf 0
    {
        float4 n0 = reinterpret_cast<const float4*>(aptr)[0];
        float4 n1 = reinterpret_cast<const float4*>(aptr)[1];
        uint4 pk;
        pk.x = f2bf(n0.x) | (f2bf(n0.y) << 16);
        pk.y = f2bf(n0.z) | (f2bf(n0.w) << 16);
        pk.z = f2bf(n1.x) | (f2bf(n1.y) << 16);
        pk.w = f2bf(n1.z) | (f2bf(n1.w) << 16);
        *reinterpret_cast<uint4*>(&a_sh[0][sidx]) = pk;
    }
    __syncthreads();

    const unsigned short* bbase = wv + (size_t)(w * 128 + col) * H_DIM + quad * 8;

    for (int ks = 0; ks < 16; ks++) {
        const int cur = ks & 1;

        // A prefetch for next K-step (issued first -> max latency cover)
        float4 n0, n1;
        if (ks < 15) {
            const float* ap = aptr + (ks + 1) * 64;
            n0 = reinterpret_cast<const float4*>(ap)[0];
            n1 = reinterpret_cast<const float4*>(ap)[1];
        }

        // B fragments for this K-step (L2-resident wv)
        bf16x8 bf[2][8];
#pragma unroll
        for (int kk = 0; kk < 2; kk++)
#pragma unroll
            for (int nt = 0; nt < 8; nt++)
                bf[kk][nt] = *reinterpret_cast<const bf16x8*>(
                    bbase + (size_t)nt * 16 * H_DIM + ks * 64 + kk * 32);

#pragma unroll
        for (int kk = 0; kk < 2; kk++) {
            bf16x8 af[4];
#pragma unroll
            for (int mt = 0; mt < 4; mt++)
                af[mt] = *reinterpret_cast<const bf16x8*>(
                    &a_sh[cur][(mt * 16 + col) * 72 + kk * 32 + quad * 8]);
#pragma unroll
            for (int nt = 0; nt < 8; nt++)
#pragma unroll
                for (int mt = 0; mt < 4; mt++)
                    acc[mt][nt] = __builtin_amdgcn_mfma_f32_16x16x32_bf16(
                        af[mt], bf[kk][nt], acc[mt][nt], 0, 0, 0);
        }

        // stage prefetched tile into the other buffer
        if (ks < 15) {
            uint4 pk;
            pk.x = f2bf(n0.x) | (f2bf(n0.y) << 16);
            pk.y = f2bf(n0.z) | (f2bf(n0.w) << 16);
            pk.z = f2bf(n1.x) | (f2bf(n1.y) << 16);
            pk.w = f2bf(n1.z) | (f2bf(n1.w) << 16);
            *reinterpret_cast<uint4*>(&a_sh[1 - cur][sidx]) = pk;
        }
        __syncthreads();
    }

    // ---- epilogue: score_m = sum_n tanh(pre + c) * Vw[n] ----
    float cv[8], vwv[8];
#pragma unroll
    for (int nt = 0; nt < 8; nt++) {
        int n = w * 128 + nt * 16 + col;
        cv[nt] = cvec[(size_t)b * U_DIM + n];
        vwv[nt] = Vw[n];
    }
#pragma unroll
    for (int mt = 0; mt < 4; mt++) {
#pragma unroll
        for (int j = 0; j < 4; j++) {
            float s = 0.f;
#pragma unroll
            for (int nt = 0; nt < 8; nt++)
                s += fast_tanh(acc[mt][nt][j] + cv[nt]) * vwv[nt];
            s += __shfl_xor(s, 1, 64);
            s += __shfl_xor(s, 2, 64);
            s += __shfl_xor(s, 4, 64);
            s += __shfl_xor(s, 8, 64);
            if (col == 0) sc_sh[(mt * 16 + quad * 4 + j) * 8 + w] = s;
        }
    }
    __syncthreads();
    if (tid < 64) {
        float s = 0.f;
#pragma unroll
        for (int ww = 0; ww < 8; ww++) s += sc_sh[tid * 8 + ww];
        score[(size_t)b * T_DIM + t0 + tid] = s;
    }
}

// ---------- pass 2: softmax over T per batch ----------
__global__ void softmax_kernel(const float* __restrict__ score,
                               float* __restrict__ aw) {
    int b = blockIdx.x;            // 32
    int tid = threadIdx.x;         // 256
    int lane = tid & 63, w = tid >> 6;
    __shared__ float redm[4];
    __shared__ float reds[4];
    float loc[8];
    float m = -1e30f;
#pragma unroll
    for (int i = 0; i < 8; i++) {
        loc[i] = score[(size_t)b * T_DIM + tid + i * 256];
        m = fmaxf(m, loc[i]);
    }
#pragma unroll
    for (int off = 32; off >= 1; off >>= 1) m = fmaxf(m, __shfl_xor(m, off, 64));
    if (lane == 0) redm[w] = m;
    __syncthreads();
    m = fmaxf(fmaxf(redm[0], redm[1]), fmaxf(redm[2], redm[3]));
    float sum = 0.f;
#pragma unroll
    for (int i = 0; i < 8; i++) {
        loc[i] = __expf(loc[i] - m);
        sum += loc[i];
    }
#pragma unroll
    for (int off = 32; off >= 1; off >>= 1) sum += __shfl_xor(sum, off, 64);
    if (lane == 0) reds[w] = sum;
    __syncthreads();
    sum = reds[0] + reds[1] + reds[2] + reds[3];
    float inv = 1.0f / sum;
#pragma unroll
    for (int i = 0; i < 8; i++)
        aw[(size_t)b * T_DIM + tid + i * 256] = loc[i] * inv;
}

// ---------- pass 3a: partial context over t-chunks ----------
__global__ void ctx_partial_kernel(const float* __restrict__ values,
                                   const float* __restrict__ aw,
                                   float* __restrict__ partial) {
    int tc = blockIdx.x;           // 16 chunks of 128 t
    int b = blockIdx.y;            // 32
    int tid = threadIdx.x;         // 256 -> h = tid*4..+3
    const float4* v4 = reinterpret_cast<const float4*>(
                           values + ((size_t)b * T_DIM + tc * 128) * H_DIM) + tid;
    const float* a = aw + (size_t)b * T_DIM + tc * 128;
    float4 acc = make_float4(0.f, 0.f, 0.f, 0.f);
#pragma unroll 4
    for (int t = 0; t < 128; t++) {
        float wgt = a[t];
        float4 vv = v4[(size_t)t * (H_DIM / 4)];
        acc.x += wgt * vv.x; acc.y += wgt * vv.y;
        acc.z += wgt * vv.z; acc.w += wgt * vv.w;
    }
    reinterpret_cast<float4*>(partial + ((size_t)b * 16 + tc) * H_DIM)[tid] = acc;
}

// ---------- pass 3b: combine partials ----------
__global__ void ctx_combine_kernel(const float* __restrict__ partial,
                                   float* __restrict__ ctx) {
    int idx = blockIdx.x * 256 + threadIdx.x;   // 32768
    int b = idx >> 10, h = idx & (H_DIM - 1);
    float s = 0.f;
#pragma unroll
    for (int tc = 0; tc < 16; tc++)
        s += partial[((size_t)b * 16 + tc) * H_DIM + h];
    ctx[idx] = s;
}

extern "C" void kernel_launch(void* const* d_in, const int* in_sizes, int n_in,
                              void* d_out, int out_size, void* d_ws, size_t ws_size,
                              hipStream_t stream) {
    const float* query  = (const float*)d_in[0];   // [1][B][H]
    const float* values = (const float*)d_in[1];   // [B][T][H]
    const float* W_w    = (const float*)d_in[2];   // [U][2H]
    const float* W_b    = (const float*)d_in[3];   // [U]
    const float* V_w    = (const float*)d_in[4];   // [1][U]
    // d_in[5] = V_b: uniform score shift, cancels in softmax -> unused.

    float* out = (float*)d_out;
    char* ws = (char*)d_ws;
    float* cvec            = (float*)(ws);                               // 128 KB
    unsigned short* wv     = (unsigned short*)(ws + 131072);             // 2 MB
    float* score           = (float*)(ws + 131072 + 2097152);            // 256 KB
    float* partial         = (float*)(ws + 131072 + 2097152 + 262144);   // 2 MB
    float* ctx = out;                    // [B][H]
    float* aw  = out + B_DIM * H_DIM;    // [B][T]

    prep_wv_kernel<<<U_DIM, 256, 0, stream>>>(W_w, wv);
    prep_c_kernel<<<dim3(U_DIM / 64, B_DIM), 256, 0, stream>>>(query, W_w, W_b, cvec);
    gemm_score_kernel<<<(B_DIM * T_DIM) / 64, 512, 0, stream>>>(values, wv, cvec, V_w, score);
    softmax_kernel<<<B_DIM, 256, 0, stream>>>(score, aw);
    ctx_partial_kernel<<<dim3(16, B_DIM), 256, 0, stream>>>(values, aw, partial);
    ctx_combine_kernel<<<128, 256, 0, stream>>>(partial, ctx);
}